// Round 9
// baseline (2783.300 us; speedup 1.0000x reference)
//
#include <hip/hip_runtime.h>
#include <hip/hip_bf16.h>

typedef unsigned int u32;
typedef unsigned short u16;

#define DEV static __device__ __forceinline__

// ---------- weight layout in ws (float offsets) ----------
#define O_G1   0        // gcn1_w  [10,64]
#define O_G1b  640      // gcn1_b  [64]
#define O_W1   704      // e_w1    [30,64]
#define O_B1   2624     // e_b1    [64]
#define O_W2t  2688     // e_w2^T  [64,64]  W2t[o*64+k] = e_w2[k,o]
#define O_B2   6784     // e_b2    [64]
#define O_G2   6848     // gcn2_w  [128,64]
#define O_G2b  15040    // gcn2_b  [64]
#define O_G3   15104    // gcn3_w  [64,10]
#define O_G3b  15744    // gcn3_b  [10]
#define O_L1   15754    // l1_w    [20,10]
#define O_L1b  15954    // l1_b    [10]
#define O_L2t  15964    // l2_w^T  [128,10] L2t[o*10+k] = l2_w[k,o]
#define O_L2b  17244    // l2_b    [128]
#define O_L3   17372    // l3_w    [128,32]
#define O_L3b  21468    // l3_b    [32]
#define O_L4t  21500    // l4_w^T  [2,32]   L4t[c*32+j] = l4_w[j,c]
#define O_L4b  21564    // l4_b    [2]
#define WTOT   21568

DEV float bfu(u16 h){ return __uint_as_float(((u32)h) << 16); }
DEV float bflo(u32 u){ return __uint_as_float(u << 16); }
DEV float bfhi(u32 u){ return __uint_as_float(u & 0xffff0000u); }
DEV u16 f2bf(float x){
  __hip_bfloat16 b = __float2bfloat16(x);
  return *(u16*)&b;
}

// dtype-flexible scalar read: flag=1 -> fp32, flag=0 -> bf16
DEV float rdf(const void* p, int idx, int isf32){
  return isf32 ? ((const float*)p)[idx] : bfu(((const u16*)p)[idx]);
}

DEV void load10_bf(const u32* __restrict__ p, float* f){
  u32 a0=p[0],a1=p[1],a2=p[2],a3=p[3],a4=p[4];
  f[0]=bflo(a0); f[1]=bfhi(a0);
  f[2]=bflo(a1); f[3]=bfhi(a1);
  f[4]=bflo(a2); f[5]=bfhi(a2);
  f[6]=bflo(a3); f[7]=bfhi(a3);
  f[8]=bflo(a4); f[9]=bfhi(a4);
}

DEV void load10_any(const void* base, size_t row, int isf32, float* f){
  if (isf32){
    const float* p = (const float*)base + row*10;
    #pragma unroll
    for (int k=0;k<10;k++) f[k] = p[k];
  } else {
    load10_bf((const u32*)base + row*5, f);
  }
}

DEV float softplusf(float x){ return fmaxf(x,0.f) + log1pf(__expf(-fabsf(x))); }

// ---------- dtype detection: per-array bf16 vs fp32, one block per array ----------
__global__ __launch_bounds__(256) void k_detect(
    const u32* p0, const u32* p1, const u32* p2, const u32* p3,
    const u32* p4, const u32* p5, const u32* p6, const u32* p7,
    const u32* p8, const u32* p9, const u32* p10,const u32* p11,
    const u32* p12,const u32* p13,const u32* p14,const u32* p15,
    const u32* p16,const u32* p17,const u32* p18,const u32* p19,
    int* __restrict__ flags, int N_, int E_)
{
  int a = blockIdx.x;
  const u32* p;
  int elems;
  switch (a){
    case 0:  p=p0;  elems=N_*10; break;
    case 1:  p=p1;  elems=E_*10; break;
    case 2:  p=p2;  elems=640;  break;
    case 3:  p=p3;  elems=64;   break;
    case 4:  p=p4;  elems=1920; break;
    case 5:  p=p5;  elems=64;   break;
    case 6:  p=p6;  elems=4096; break;
    case 7:  p=p7;  elems=64;   break;
    case 8:  p=p8;  elems=8192; break;
    case 9:  p=p9;  elems=64;   break;
    case 10: p=p10; elems=640;  break;
    case 11: p=p11; elems=10;   break;
    case 12: p=p12; elems=200;  break;
    case 13: p=p13; elems=10;   break;
    case 14: p=p14; elems=1280; break;
    case 15: p=p15; elems=128;  break;
    case 16: p=p16; elems=4096; break;
    case 17: p=p17; elems=32;   break;
    case 18: p=p18; elems=64;   break;
    default: p=p19; elems=2;    break;
  }
  int nw = elems/2; if (nw > 512) nw = 512; if (nw < 1) nw = 1;
  int localA = 0, localZ = 0;
  for (int i=threadIdx.x; i<nw; i+=256){
    u32 w = p[i];
    u32 ex = (w >> 7) & 0xffu;
    if (ex >= 0x90u) localA++;
    if ((w & 0xffffu) == 0u) localZ++;
  }
  int packed = (localA << 16) | localZ;
  __shared__ int red[4];
  #pragma unroll
  for (int off=32; off; off>>=1) packed += __shfl_down(packed, off);
  if ((threadIdx.x & 63) == 0) red[threadIdx.x>>6] = packed;
  __syncthreads();
  if (threadIdx.x == 0){
    int s = red[0]+red[1]+red[2]+red[3];
    int sA = s >> 16, sZ = s & 0xffff;
    flags[a] = (sA * 16 >= nw || sZ * 4 >= nw * 3) ? 1 : 0;
  }
}

// ---------- weight prep: (bf16|fp32) -> f32 (+ transposes) ----------
__global__ __launch_bounds__(256) void k_prep(
    const void* g1w, const void* g1b, const void* ew1, const void* eb1,
    const void* ew2, const void* eb2, const void* g2w, const void* g2b,
    const void* g3w, const void* g3b, const void* l1w, const void* l1b,
    const void* l2w, const void* l2b, const void* l3w, const void* l3b,
    const void* l4w, const void* l4b,
    const int* __restrict__ flags, float* __restrict__ W)
{
  int t = threadIdx.x;
  int f2=flags[2],f3=flags[3],f4=flags[4],f5=flags[5],f6=flags[6],f7=flags[7];
  int f8=flags[8],f9=flags[9],f10=flags[10],f11=flags[11],f12=flags[12],f13=flags[13];
  int f14=flags[14],f15=flags[15],f16=flags[16],f17=flags[17],f18=flags[18],f19=flags[19];
  for (int i=t;i<640;i+=256)  W[O_G1+i]  = rdf(g1w,i,f2);
  for (int i=t;i<64;i+=256)   W[O_G1b+i] = rdf(g1b,i,f3);
  for (int i=t;i<1920;i+=256) W[O_W1+i]  = rdf(ew1,i,f4);
  for (int i=t;i<64;i+=256)   W[O_B1+i]  = rdf(eb1,i,f5);
  for (int i=t;i<4096;i+=256){ int o=i>>6,k=i&63; W[O_W2t+i]=rdf(ew2,k*64+o,f6); }
  for (int i=t;i<64;i+=256)   W[O_B2+i]  = rdf(eb2,i,f7);
  for (int i=t;i<8192;i+=256) W[O_G2+i]  = rdf(g2w,i,f8);
  for (int i=t;i<64;i+=256)   W[O_G2b+i] = rdf(g2b,i,f9);
  for (int i=t;i<640;i+=256)  W[O_G3+i]  = rdf(g3w,i,f10);
  for (int i=t;i<10;i+=256)   W[O_G3b+i] = rdf(g3b,i,f11);
  for (int i=t;i<200;i+=256)  W[O_L1+i]  = rdf(l1w,i,f12);
  for (int i=t;i<10;i+=256)   W[O_L1b+i] = rdf(l1b,i,f13);
  for (int i=t;i<1280;i+=256){ int o=i/10,k=i-o*10; W[O_L2t+i]=rdf(l2w,k*128+o,f14); }
  for (int i=t;i<128;i+=256)  W[O_L2b+i] = rdf(l2b,i,f15);
  for (int i=t;i<4096;i+=256) W[O_L3+i]  = rdf(l3w,i,f16);
  for (int i=t;i<32;i+=256)   W[O_L3b+i] = rdf(l3b,i,f17);
  for (int i=t;i<64;i+=256){ int c=i>>5,j=i&31; W[O_L4t+i]=rdf(l4w,j*2+c,f18); }
  for (int i=t;i<2;i+=256)    W[O_L4b+i] = rdf(l4b,i,f19);
}

// ---------- init: zero oute (uint bits of relu'd max) and cnt ----------
__global__ __launch_bounds__(256) void k_init(u32* __restrict__ oute, int* __restrict__ cnt, int N_)
{
  int i = blockIdx.x*256 + threadIdx.x;
  if (i < N_*64) oute[i] = 0u;
  if (i < N_)    cnt[i] = 0;
}

// ---------- degree histogram over dst ----------
__global__ __launch_bounds__(256) void k_count(const int* __restrict__ ei, int* __restrict__ cnt, int E_)
{
  int e = blockIdx.x*256 + threadIdx.x;
  if (e >= E_) return;
  atomicAdd(&cnt[ei[E_+e]], 1);
}

// ---------- per-1024-block sums ----------
__global__ __launch_bounds__(1024) void k_bsum(const int* __restrict__ cnt, int* __restrict__ bsum, int N_)
{
  int i = blockIdx.x*1024 + threadIdx.x;
  int v = (i < N_) ? cnt[i] : 0;
  #pragma unroll
  for (int off=32; off; off>>=1) v += __shfl_down(v, off);
  __shared__ int ws_[16];
  if ((threadIdx.x & 63) == 0) ws_[threadIdx.x>>6] = v;
  __syncthreads();
  if (threadIdx.x == 0){
    int s = 0;
    #pragma unroll
    for (int j=0;j<16;j++) s += ws_[j];
    bsum[blockIdx.x] = s;
  }
}

// ---------- exclusive scan of block sums (NB <= 128) ----------
__global__ __launch_bounds__(128) void k_scan_small(const int* __restrict__ bsum, int* __restrict__ boff, int NB)
{
  int t = threadIdx.x;
  int v = (t < NB) ? bsum[t] : 0;
  int lane = t & 63, w = t >> 6;
  int x = v;
  #pragma unroll
  for (int off=1; off<64; off<<=1){ int y=__shfl_up(x,off); if (lane>=off) x+=y; }
  __shared__ int t2[2];
  if (lane==63) t2[w]=x;
  __syncthreads();
  if (w==1) x += t2[0];
  boff[t] = x - v;
}

// ---------- final scan: row_ptr, dis, reset cnt ----------
__global__ __launch_bounds__(1024) void k_scan_final(
    int* __restrict__ cnt, const int* __restrict__ boff,
    int* __restrict__ rp, float* __restrict__ dis, int N_, int E_)
{
  int i = blockIdx.x*1024 + threadIdx.x;
  int v = (i < N_) ? cnt[i] : 0;
  int lane = threadIdx.x & 63, w = threadIdx.x >> 6;
  int x = v;
  #pragma unroll
  for (int off=1; off<64; off<<=1){ int y=__shfl_up(x,off); if (lane>=off) x+=y; }
  __shared__ int wp[16];
  if (lane==63) wp[w]=x;
  __syncthreads();
  if (threadIdx.x==0){
    int run=0;
    #pragma unroll
    for (int j=0;j<16;j++){ int t=wp[j]; wp[j]=run; run+=t; }
  }
  __syncthreads();
  int incl = x + wp[w] + boff[blockIdx.x];
  if (i < N_){
    rp[i]  = incl - v;
    dis[i] = rsqrtf(1.f + (float)v);
    cnt[i] = 0;
  }
  if (i == 0) rp[N_] = E_;
}

// ---------- CSR fill: src ids ----------
__global__ __launch_bounds__(256) void k_fill(
    const int* __restrict__ ei, const int* __restrict__ rp, int* __restrict__ cnt,
    int* __restrict__ csrc, int E_)
{
  int e = blockIdx.x*256 + threadIdx.x;
  if (e >= E_) return;
  int s = ei[e], d = ei[E_+e];
  int pos = rp[d] + atomicAdd(&cnt[d], 1);
  csrc[pos] = s;
}

// ---------- EdgeConv MLP per edge + atomicMax(relu(m)) ----------
__global__ __launch_bounds__(256) void k_edgeconv(
    const void* __restrict__ xv, const void* __restrict__ eav,
    const int* __restrict__ ei, const float* __restrict__ W,
    const int* __restrict__ flags, u32* __restrict__ oute, int E_)
{
  int e = blockIdx.x*256 + threadIdx.x;
  if (e >= E_) return;
  int fx = flags[0], fea = flags[1];
  int s = ei[e], d = ei[E_+e];
  float in[30];
  load10_any(xv, (size_t)d, fx, in);        // x_i = x[dst]
  load10_any(xv, (size_t)s, fx, in+10);     // x_j = x[src]
  load10_any(eav, (size_t)e, fea, in+20);   // edge_attr
  const float* __restrict__ W1  = W + O_W1;
  const float* __restrict__ B1  = W + O_B1;
  const float* __restrict__ W2t = W + O_W2t;
  const float* __restrict__ B2  = W + O_B2;
  float hid[64];
  #pragma unroll
  for (int h=0;h<64;h++) hid[h] = B1[h];
  #pragma unroll
  for (int k=0;k<30;k++){
    float v = in[k];
    #pragma unroll
    for (int h=0;h<64;h++) hid[h] = fmaf(v, W1[k*64+h], hid[h]);
  }
  #pragma unroll
  for (int h=0;h<64;h++) hid[h] = fmaxf(hid[h], 0.f);
  u32* orow = oute + (size_t)d*64;
  #pragma unroll 1
  for (int o=0;o<64;o++){
    float m = B2[o];
    const float* __restrict__ w = W2t + o*64;
    #pragma unroll
    for (int k=0;k<64;k++) m = fmaf(hid[k], w[k], m);
    if (m > 0.f) atomicMax(orow + o, __float_as_uint(m));  // relu(max)=max(relu), init 0
  }
}

// ---------- gcn1 pre-agg: sx = S*x (10-wide), thread per node ----------
__global__ __launch_bounds__(256) void k_aggx(
    const void* __restrict__ xv, const int* __restrict__ rp,
    const int* __restrict__ csrc, const float* __restrict__ dis,
    const int* __restrict__ flags, float* __restrict__ sx, int N_)
{
  int i = blockIdx.x*256 + threadIdx.x;
  if (i >= N_) return;
  int fx = flags[0];
  float di = dis[i], d2 = di*di;
  float acc[10], t[10];
  load10_any(xv, (size_t)i, fx, t);
  #pragma unroll
  for (int f=0;f<10;f++) acc[f] = t[f]*d2;
  int b = rp[i], en = rp[i+1];
  for (int p=b; p<en; p++){
    int s2 = csrc[p]; float nm = dis[s2]*di;
    load10_any(xv, (size_t)s2, fx, t);
    #pragma unroll
    for (int f=0;f<10;f++) acc[f] = fmaf(t[f], nm, acc[f]);
  }
  float* o = sx + (size_t)i*10;
  #pragma unroll
  for (int f=0;f<10;f++) o[f] = acc[f];
}

// ---------- hw2 = relu(sx@G1+G1b)@G2top + oute@G2bot -> bf16 ----------
__global__ __launch_bounds__(256) void k_hw2(
    const float* __restrict__ sx, const u32* __restrict__ oute,
    const float* __restrict__ W, u16* __restrict__ hw2o, int N_)
{
  int i = blockIdx.x*256 + threadIdx.x;
  if (i >= N_) return;
  float sv[10];
  const float* srow = sx + (size_t)i*10;
  #pragma unroll
  for (int f=0;f<10;f++) sv[f] = srow[f];
  const float* __restrict__ G1  = W + O_G1;
  const float* __restrict__ G1b = W + O_G1b;
  const float* __restrict__ G2  = W + O_G2;
  float hw[64];
  #pragma unroll
  for (int f=0;f<64;f++) hw[f] = 0.f;
  #pragma unroll 1
  for (int k=0;k<64;k++){
    float o1 = G1b[k];
    #pragma unroll
    for (int j=0;j<10;j++) o1 = fmaf(sv[j], G1[j*64+k], o1);
    o1 = fmaxf(o1, 0.f);
    const float* __restrict__ wt = G2 + k*64;
    #pragma unroll
    for (int f=0;f<64;f++) hw[f] = fmaf(o1, wt[f], hw[f]);
  }
  const u32* orow = oute + (size_t)i*64;
  #pragma unroll 1
  for (int k=0;k<64;k++){
    float ov = __uint_as_float(orow[k]);   // relu'd max (0 for isolated)
    const float* __restrict__ wb = G2 + (64+k)*64;
    #pragma unroll
    for (int f=0;f<64;f++) hw[f] = fmaf(ov, wb[f], hw[f]);
  }
  u16* out = hw2o + (size_t)i*64;
  #pragma unroll
  for (int f=0;f<64;f++) out[f] = f2bf(hw[f]);
}

// ---------- gcn2 aggregation: wave per node, lane = feature ----------
__global__ __launch_bounds__(256) void k_agg64(
    const u16* __restrict__ hw2, const int* __restrict__ rp,
    const int* __restrict__ csrc, const float* __restrict__ dis,
    const float* __restrict__ W, float* __restrict__ out2, int N_)
{
  int i = (blockIdx.x*256 + threadIdx.x) >> 6;
  int lane = threadIdx.x & 63;
  if (i >= N_) return;
  float di = dis[i];
  float acc = bfu(hw2[(size_t)i*64 + lane]) * di * di;
  int b = rp[i], en = rp[i+1];
  for (int p=b; p<en; p++){
    int s2 = csrc[p]; float nm = dis[s2]*di;
    acc = fmaf(bfu(hw2[(size_t)s2*64 + lane]), nm, acc);   // 128B coalesced per edge
  }
  float o2 = fmaxf(acc + (W+O_G2b)[lane], 0.f);
  out2[(size_t)i*64 + lane] = o2;
}

// ---------- hw3 = out2 @ gcn3_w (64->10), thread per node ----------
__global__ __launch_bounds__(256) void k_hw3(
    const float* __restrict__ out2, const float* __restrict__ W,
    float* __restrict__ hw3, int N_)
{
  int i = blockIdx.x*256 + threadIdx.x;
  if (i >= N_) return;
  const float* row = out2 + (size_t)i*64;
  const float* __restrict__ G3 = W + O_G3;
  float a[10];
  #pragma unroll
  for (int f=0;f<10;f++) a[f] = 0.f;
  #pragma unroll 1
  for (int k=0;k<64;k++){
    float v = row[k];
    const float* __restrict__ w = G3 + k*10;
    #pragma unroll
    for (int f=0;f<10;f++) a[f] = fmaf(v, w[f], a[f]);
  }
  float* o = hw3 + (size_t)i*10;
  #pragma unroll
  for (int f=0;f<10;f++) o[f] = a[f];
}

// ---------- gcn3 aggregation + MLP head -> FP32 output ----------
__global__ __launch_bounds__(256) void k_final(
    const void* __restrict__ xv, const float* __restrict__ hw3,
    const int* __restrict__ rp, const int* __restrict__ csrc,
    const float* __restrict__ dis, const int* __restrict__ flags,
    const float* __restrict__ W, float* __restrict__ out, int N_)
{
  int i = blockIdx.x*256 + threadIdx.x;
  if (i >= N_) return;
  int fx = flags[0];
  float di = dis[i];
  float a[10];
  const float* hrow = hw3 + (size_t)i*10;
  #pragma unroll
  for (int f=0;f<10;f++) a[f] = hrow[f]*di*di;
  int b = rp[i], en = rp[i+1];
  for (int p=b; p<en; p++){
    int s2 = csrc[p]; float nm = dis[s2]*di;
    const float* r2 = hw3 + (size_t)s2*10;
    #pragma unroll
    for (int f=0;f<10;f++) a[f] = fmaf(r2[f], nm, a[f]);
  }
  const float* G3b = W + O_G3b;
  float h20[20];
  load10_any(xv, (size_t)i, fx, h20);                  // concat: x first
  #pragma unroll
  for (int f=0;f<10;f++) h20[10+f] = fmaxf(a[f] + G3b[f], 0.f);  // out3
  // l1
  const float* __restrict__ L1  = W + O_L1;
  const float* __restrict__ L1b = W + O_L1b;
  float h1[10];
  #pragma unroll
  for (int f=0;f<10;f++) h1[f] = L1b[f];
  #pragma unroll
  for (int k=0;k<20;k++){
    float v = h20[k];
    const float* __restrict__ w = L1 + k*10;
    #pragma unroll
    for (int f=0;f<10;f++) h1[f] = fmaf(v, w[f], h1[f]);
  }
  #pragma unroll
  for (int f=0;f<10;f++) h1[f] = softplusf(h1[f]);
  // l2 streamed into l3 accumulators
  const float* __restrict__ L2t = W + O_L2t;
  const float* __restrict__ L2b = W + O_L2b;
  const float* __restrict__ L3  = W + O_L3;
  const float* __restrict__ L3b = W + O_L3b;
  float h3a[32];
  #pragma unroll
  for (int j=0;j<32;j++) h3a[j] = L3b[j];
  #pragma unroll 1
  for (int o=0;o<128;o++){
    float s2 = L2b[o];
    const float* __restrict__ wt = L2t + o*10;
    #pragma unroll
    for (int k=0;k<10;k++) s2 = fmaf(h1[k], wt[k], s2);
    s2 = softplusf(s2);
    const float* __restrict__ w3 = L3 + o*32;
    #pragma unroll
    for (int j=0;j<32;j++) h3a[j] = fmaf(s2, w3[j], h3a[j]);
  }
  const float* L4t = W + O_L4t;
  const float* L4b = W + O_L4b;
  float r0 = L4b[0], r1 = L4b[1];
  #pragma unroll
  for (int j=0;j<32;j++){
    float h3 = softplusf(h3a[j]);
    r0 = fmaf(h3, L4t[j],    r0);
    r1 = fmaf(h3, L4t[32+j], r1);
  }
  out[i]      = r0;   // fp32 output (reference returns float32)
  out[N_ + i] = r1;
}

extern "C" void kernel_launch(void* const* d_in, const int* in_sizes, int n_in,
                              void* d_out, int out_size, void* d_ws, size_t ws_size,
                              hipStream_t stream)
{
  const void* xv  = d_in[0];
  const void* eav = d_in[1];
  const int*  ei  = (const int*)d_in[20];
  int N_ = in_sizes[0] / 10;
  int E_ = in_sizes[1] / 10;

  float* W = (float*)d_ws;
  size_t off = WTOT;
  int*   cnt   = (int*)(W + off);   off += (size_t)N_;
  int*   rp    = (int*)(W + off);   off += (size_t)N_ + 1;
  float* dis   = (float*)(W + off); off += (size_t)N_;
  int*   bsum  = (int*)(W + off);   off += 256;
  int*   boff  = (int*)(W + off);   off += 256;
  int*   flags = (int*)(W + off);   off += 32;
  int*   csrc  = (int*)(W + off);   off += (size_t)E_;
  u32*   oute  = (u32*)(W + off);            // [N,64] f32 bits; reused as out2 after k_hw2
  float* out2  = (float*)oute;
  off += (size_t)N_ * 64;
  u16*   hw2   = (u16*)(W + off);   off += (size_t)N_ * 32;   // [N,64] bf16
  float* sx    = (float*)(W + off);          // [N,10]; reused as hw3 after k_hw2
  float* hw3   = sx;
  off += (size_t)N_ * 10;

  if (ws_size < off * sizeof(float)) return;

  int gN = (N_ + 255)/256, gE = (E_ + 255)/256, gI = (N_*64 + 255)/256;
  int NB = (N_ + 1023)/1024;

  k_detect<<<20,256,0,stream>>>(
      (const u32*)d_in[0],(const u32*)d_in[1],
      (const u32*)d_in[2],(const u32*)d_in[3],(const u32*)d_in[4],(const u32*)d_in[5],
      (const u32*)d_in[6],(const u32*)d_in[7],(const u32*)d_in[8],(const u32*)d_in[9],
      (const u32*)d_in[10],(const u32*)d_in[11],(const u32*)d_in[12],(const u32*)d_in[13],
      (const u32*)d_in[14],(const u32*)d_in[15],(const u32*)d_in[16],(const u32*)d_in[17],
      (const u32*)d_in[18],(const u32*)d_in[19],
      flags, N_, E_);
  k_prep<<<1,256,0,stream>>>(
      d_in[2],d_in[3],d_in[4],d_in[5],d_in[6],d_in[7],d_in[8],d_in[9],
      d_in[10],d_in[11],d_in[12],d_in[13],d_in[14],d_in[15],d_in[16],d_in[17],
      d_in[18],d_in[19], flags, W);
  k_init<<<gI,256,0,stream>>>(oute, cnt, N_);
  k_count<<<gE,256,0,stream>>>(ei, cnt, E_);
  k_bsum<<<NB,1024,0,stream>>>(cnt, bsum, N_);
  k_scan_small<<<1,128,0,stream>>>(bsum, boff, NB);
  k_scan_final<<<NB,1024,0,stream>>>(cnt, boff, rp, dis, N_, E_);
  k_fill<<<gE,256,0,stream>>>(ei, rp, cnt, csrc, E_);
  k_edgeconv<<<gE,256,0,stream>>>(xv, eav, ei, W, flags, oute, E_);
  k_aggx<<<gN,256,0,stream>>>(xv, rp, csrc, dis, flags, sx, N_);
  k_hw2<<<gN,256,0,stream>>>(sx, oute, W, hw2, N_);
  k_agg64<<<(N_+3)/4,256,0,stream>>>(hw2, rp, csrc, dis, W, out2, N_);
  k_hw3<<<gN,256,0,stream>>>(out2, W, hw3, N_);
  k_final<<<gN,256,0,stream>>>(xv, hw3, rp, csrc, dis, flags, W,
                               (float*)d_out, N_);
}

// Round 10
// 1445.251 us; speedup vs baseline: 1.9258x; 1.9258x over previous
//
#include <hip/hip_runtime.h>
#include <hip/hip_bf16.h>

typedef unsigned int u32;
typedef unsigned short u16;

#define DEV static __device__ __forceinline__

// ---------- weight layout in ws (float offsets) ----------
#define O_G1   0        // gcn1_w  [10,64]
#define O_G1b  640      // gcn1_b  [64]
#define O_W1   704      // e_w1    [30,64]
#define O_B1   2624     // e_b1    [64]
#define O_W2   2688     // e_w2    [64,64] natural [k][o] layout (coalesced col reads)
#define O_B2   6784     // e_b2    [64]
#define O_G2   6848     // gcn2_w  [128,64]
#define O_G2b  15040    // gcn2_b  [64]
#define O_G3   15104    // gcn3_w  [64,10]
#define O_G3b  15744    // gcn3_b  [10]
#define O_L1   15754    // l1_w    [20,10]
#define O_L1b  15954    // l1_b    [10]
#define O_L2t  15964    // l2_w^T  [128,10]
#define O_L2b  17244    // l2_b    [128]
#define O_L3   17372    // l3_w    [128,32]
#define O_L3b  21468    // l3_b    [32]
#define O_L4t  21500    // l4_w^T  [2,32]
#define O_L4b  21564    // l4_b    [2]
#define WTOT   21568

DEV float bfu(u16 h){ return __uint_as_float(((u32)h) << 16); }
DEV float bflo(u32 u){ return __uint_as_float(u << 16); }
DEV float bfhi(u32 u){ return __uint_as_float(u & 0xffff0000u); }
DEV u16 f2bf(float x){
  __hip_bfloat16 b = __float2bfloat16(x);
  return *(u16*)&b;
}
DEV float rdf(const void* p, int idx, int isf32){
  return isf32 ? ((const float*)p)[idx] : bfu(((const u16*)p)[idx]);
}
DEV void load10_bf(const u32* __restrict__ p, float* f){
  u32 a0=p[0],a1=p[1],a2=p[2],a3=p[3],a4=p[4];
  f[0]=bflo(a0); f[1]=bfhi(a0);
  f[2]=bflo(a1); f[3]=bfhi(a1);
  f[4]=bflo(a2); f[5]=bfhi(a2);
  f[6]=bflo(a3); f[7]=bfhi(a3);
  f[8]=bflo(a4); f[9]=bfhi(a4);
}
DEV void load10_any(const void* base, size_t row, int isf32, float* f){
  if (isf32){
    const float* p = (const float*)base + row*10;
    #pragma unroll
    for (int k=0;k<10;k++) f[k] = p[k];
  } else {
    load10_bf((const u32*)base + row*5, f);
  }
}
DEV float softplusf(float x){ return fmaxf(x,0.f) + log1pf(__expf(-fabsf(x))); }

// ---------- dtype detection: per-array bf16 vs fp32, one block per array ----------
__global__ __launch_bounds__(256) void k_detect(
    const u32* p0, const u32* p1, const u32* p2, const u32* p3,
    const u32* p4, const u32* p5, const u32* p6, const u32* p7,
    const u32* p8, const u32* p9, const u32* p10,const u32* p11,
    const u32* p12,const u32* p13,const u32* p14,const u32* p15,
    const u32* p16,const u32* p17,const u32* p18,const u32* p19,
    int* __restrict__ flags, int N_, int E_)
{
  int a = blockIdx.x;
  const u32* p;
  int elems;
  switch (a){
    case 0:  p=p0;  elems=N_*10; break;
    case 1:  p=p1;  elems=E_*10; break;
    case 2:  p=p2;  elems=640;  break;
    case 3:  p=p3;  elems=64;   break;
    case 4:  p=p4;  elems=1920; break;
    case 5:  p=p5;  elems=64;   break;
    case 6:  p=p6;  elems=4096; break;
    case 7:  p=p7;  elems=64;   break;
    case 8:  p=p8;  elems=8192; break;
    case 9:  p=p9;  elems=64;   break;
    case 10: p=p10; elems=640;  break;
    case 11: p=p11; elems=10;   break;
    case 12: p=p12; elems=200;  break;
    case 13: p=p13; elems=10;   break;
    case 14: p=p14; elems=1280; break;
    case 15: p=p15; elems=128;  break;
    case 16: p=p16; elems=4096; break;
    case 17: p=p17; elems=32;   break;
    case 18: p=p18; elems=64;   break;
    default: p=p19; elems=2;    break;
  }
  int nw = elems/2; if (nw > 512) nw = 512; if (nw < 1) nw = 1;
  int localA = 0, localZ = 0;
  for (int i=threadIdx.x; i<nw; i+=256){
    u32 w = p[i];
    u32 ex = (w >> 7) & 0xffu;
    if (ex >= 0x90u) localA++;
    if ((w & 0xffffu) == 0u) localZ++;
  }
  int packed = (localA << 16) | localZ;
  __shared__ int red[4];
  #pragma unroll
  for (int off=32; off; off>>=1) packed += __shfl_down(packed, off);
  if ((threadIdx.x & 63) == 0) red[threadIdx.x>>6] = packed;
  __syncthreads();
  if (threadIdx.x == 0){
    int s = red[0]+red[1]+red[2]+red[3];
    int sA = s >> 16, sZ = s & 0xffff;
    flags[a] = (sA * 16 >= nw || sZ * 4 >= nw * 3) ? 1 : 0;
  }
}

// ---------- weight prep ----------
__global__ __launch_bounds__(256) void k_prep(
    const void* g1w, const void* g1b, const void* ew1, const void* eb1,
    const void* ew2, const void* eb2, const void* g2w, const void* g2b,
    const void* g3w, const void* g3b, const void* l1w, const void* l1b,
    const void* l2w, const void* l2b, const void* l3w, const void* l3b,
    const void* l4w, const void* l4b,
    const int* __restrict__ flags, float* __restrict__ W)
{
  int t = threadIdx.x;
  int f2=flags[2],f3=flags[3],f4=flags[4],f5=flags[5],f6=flags[6],f7=flags[7];
  int f8=flags[8],f9=flags[9],f10=flags[10],f11=flags[11],f12=flags[12],f13=flags[13];
  int f14=flags[14],f15=flags[15],f16=flags[16],f17=flags[17],f18=flags[18],f19=flags[19];
  for (int i=t;i<640;i+=256)  W[O_G1+i]  = rdf(g1w,i,f2);
  for (int i=t;i<64;i+=256)   W[O_G1b+i] = rdf(g1b,i,f3);
  for (int i=t;i<1920;i+=256) W[O_W1+i]  = rdf(ew1,i,f4);
  for (int i=t;i<64;i+=256)   W[O_B1+i]  = rdf(eb1,i,f5);
  for (int i=t;i<4096;i+=256) W[O_W2+i]  = rdf(ew2,i,f6);   // natural [k][o]
  for (int i=t;i<64;i+=256)   W[O_B2+i]  = rdf(eb2,i,f7);
  for (int i=t;i<8192;i+=256) W[O_G2+i]  = rdf(g2w,i,f8);
  for (int i=t;i<64;i+=256)   W[O_G2b+i] = rdf(g2b,i,f9);
  for (int i=t;i<640;i+=256)  W[O_G3+i]  = rdf(g3w,i,f10);
  for (int i=t;i<10;i+=256)   W[O_G3b+i] = rdf(g3b,i,f11);
  for (int i=t;i<200;i+=256)  W[O_L1+i]  = rdf(l1w,i,f12);
  for (int i=t;i<10;i+=256)   W[O_L1b+i] = rdf(l1b,i,f13);
  for (int i=t;i<1280;i+=256){ int o=i/10,k=i-o*10; W[O_L2t+i]=rdf(l2w,k*128+o,f14); }
  for (int i=t;i<128;i+=256)  W[O_L2b+i] = rdf(l2b,i,f15);
  for (int i=t;i<4096;i+=256) W[O_L3+i]  = rdf(l3w,i,f16);
  for (int i=t;i<32;i+=256)   W[O_L3b+i] = rdf(l3b,i,f17);
  for (int i=t;i<64;i+=256){ int c=i>>5,j=i&31; W[O_L4t+i]=rdf(l4w,j*2+c,f18); }
  for (int i=t;i<2;i+=256)    W[O_L4b+i] = rdf(l4b,i,f19);
}

// ---------- init: zero cnt ----------
__global__ __launch_bounds__(256) void k_init(int* __restrict__ cnt, int N_)
{
  int i = blockIdx.x*256 + threadIdx.x;
  if (i < N_) cnt[i] = 0;
}

// ---------- degree histogram over dst ----------
__global__ __launch_bounds__(256) void k_count(const int* __restrict__ ei, int* __restrict__ cnt, int E_)
{
  int e = blockIdx.x*256 + threadIdx.x;
  if (e >= E_) return;
  atomicAdd(&cnt[ei[E_+e]], 1);
}

// ---------- per-1024-block sums ----------
__global__ __launch_bounds__(1024) void k_bsum(const int* __restrict__ cnt, int* __restrict__ bsum, int N_)
{
  int i = blockIdx.x*1024 + threadIdx.x;
  int v = (i < N_) ? cnt[i] : 0;
  #pragma unroll
  for (int off=32; off; off>>=1) v += __shfl_down(v, off);
  __shared__ int ws_[16];
  if ((threadIdx.x & 63) == 0) ws_[threadIdx.x>>6] = v;
  __syncthreads();
  if (threadIdx.x == 0){
    int s = 0;
    #pragma unroll
    for (int j=0;j<16;j++) s += ws_[j];
    bsum[blockIdx.x] = s;
  }
}

// ---------- exclusive scan of block sums (NB <= 128) ----------
__global__ __launch_bounds__(128) void k_scan_small(const int* __restrict__ bsum, int* __restrict__ boff, int NB)
{
  int t = threadIdx.x;
  int v = (t < NB) ? bsum[t] : 0;
  int lane = t & 63, w = t >> 6;
  int x = v;
  #pragma unroll
  for (int off=1; off<64; off<<=1){ int y=__shfl_up(x,off); if (lane>=off) x+=y; }
  __shared__ int t2[2];
  if (lane==63) t2[w]=x;
  __syncthreads();
  if (w==1) x += t2[0];
  boff[t] = x - v;
}

// ---------- final scan: row_ptr, dis, reset cnt ----------
__global__ __launch_bounds__(1024) void k_scan_final(
    int* __restrict__ cnt, const int* __restrict__ boff,
    int* __restrict__ rp, float* __restrict__ dis, int N_, int E_)
{
  int i = blockIdx.x*1024 + threadIdx.x;
  int v = (i < N_) ? cnt[i] : 0;
  int lane = threadIdx.x & 63, w = threadIdx.x >> 6;
  int x = v;
  #pragma unroll
  for (int off=1; off<64; off<<=1){ int y=__shfl_up(x,off); if (lane>=off) x+=y; }
  __shared__ int wp[16];
  if (lane==63) wp[w]=x;
  __syncthreads();
  if (threadIdx.x==0){
    int run=0;
    #pragma unroll
    for (int j=0;j<16;j++){ int t=wp[j]; wp[j]=run; run+=t; }
  }
  __syncthreads();
  int incl = x + wp[w] + boff[blockIdx.x];
  if (i < N_){
    rp[i]  = incl - v;
    dis[i] = rsqrtf(1.f + (float)v);
    cnt[i] = 0;
  }
  if (i == 0) rp[N_] = E_;
}

// ---------- CSR fill: src ids + edge ids ----------
__global__ __launch_bounds__(256) void k_fill(
    const int* __restrict__ ei, const int* __restrict__ rp, int* __restrict__ cnt,
    int* __restrict__ csrc, int* __restrict__ cedge, int E_)
{
  int e = blockIdx.x*256 + threadIdx.x;
  if (e >= E_) return;
  int s = ei[e], d = ei[E_+e];
  int pos = rp[d] + atomicAdd(&cnt[d], 1);
  csrc[pos]  = s;
  cedge[pos] = e;
}

// ---------- EdgeConv: wave-per-node cooperative gather-max (NO atomics) ----------
// lane = hidden/output channel. Per-lane weight columns in VGPRs.
// Edge inputs loaded via wave-uniform (readfirstlane) addresses -> scalar loads.
// hid broadcast via v_readlane (unrolled const index). relu(max)=max(0-init, m).
__global__ __launch_bounds__(256) void k_edgeconv(
    const void* __restrict__ xv, const void* __restrict__ eav,
    const int* __restrict__ rp, const int* __restrict__ csrc,
    const int* __restrict__ cedge, const float* __restrict__ W,
    const int* __restrict__ flags, float* __restrict__ oute, int N_)
{
  int lane = threadIdx.x & 63;
  int node = blockIdx.x*4 + (threadIdx.x >> 6);
  if (node >= N_) return;                       // wave-uniform exit
  int fx = flags[0], fea = flags[1];
  // per-lane weight columns (coalesced: lane varies fastest)
  float w1c[30], w2c[64];
  #pragma unroll
  for (int k=0;k<30;k++) w1c[k] = (W+O_W1)[k*64+lane];
  #pragma unroll
  for (int k=0;k<64;k++) w2c[k] = (W+O_W2)[k*64+lane];
  float b1v = (W+O_B1)[lane], b2v = (W+O_B2)[lane];
  int un = __builtin_amdgcn_readfirstlane(node);
  float xd[10];
  load10_any(xv, (size_t)un, fx, xd);           // uniform -> scalar loads
  int b  = __builtin_amdgcn_readfirstlane(rp[un]);
  int en = __builtin_amdgcn_readfirstlane(rp[un+1]);
  float acc = 0.f;
  for (int p=b; p<en; p++){
    int s = __builtin_amdgcn_readfirstlane(csrc[p]);
    int e = __builtin_amdgcn_readfirstlane(cedge[p]);
    float in20[20];
    load10_any(xv, (size_t)s, fx, in20);        // x_j
    load10_any(eav, (size_t)e, fea, in20+10);   // edge_attr
    float h = b1v;
    #pragma unroll
    for (int k=0;k<10;k++) h = fmaf(xd[k],   w1c[k],    h);
    #pragma unroll
    for (int k=0;k<20;k++) h = fmaf(in20[k], w1c[10+k], h);
    h = fmaxf(h, 0.f);
    float m = b2v;
    #pragma unroll
    for (int k=0;k<64;k++){
      float hk = __int_as_float(__builtin_amdgcn_readlane(__float_as_int(h), k));
      m = fmaf(hk, w2c[k], m);
    }
    acc = fmaxf(acc, m);
  }
  oute[(size_t)node*64 + lane] = acc;           // coalesced row write
}

// ---------- gcn1 pre-agg: sx = S*x (10-wide), thread per node ----------
__global__ __launch_bounds__(256) void k_aggx(
    const void* __restrict__ xv, const int* __restrict__ rp,
    const int* __restrict__ csrc, const float* __restrict__ dis,
    const int* __restrict__ flags, float* __restrict__ sx, int N_)
{
  int i = blockIdx.x*256 + threadIdx.x;
  if (i >= N_) return;
  int fx = flags[0];
  float di = dis[i], d2 = di*di;
  float acc[10], t[10];
  load10_any(xv, (size_t)i, fx, t);
  #pragma unroll
  for (int f=0;f<10;f++) acc[f] = t[f]*d2;
  int b = rp[i], en = rp[i+1];
  for (int p=b; p<en; p++){
    int s2 = csrc[p]; float nm = dis[s2]*di;
    load10_any(xv, (size_t)s2, fx, t);
    #pragma unroll
    for (int f=0;f<10;f++) acc[f] = fmaf(t[f], nm, acc[f]);
  }
  float* o = sx + (size_t)i*10;
  #pragma unroll
  for (int f=0;f<10;f++) o[f] = acc[f];
}

// ---------- hw2 = relu(sx@G1+G1b)@G2top + oute@G2bot -> bf16 ----------
__global__ __launch_bounds__(256) void k_hw2(
    const float* __restrict__ sx, const float* __restrict__ oute,
    const float* __restrict__ W, u16* __restrict__ hw2o, int N_)
{
  int i = blockIdx.x*256 + threadIdx.x;
  if (i >= N_) return;
  float sv[10];
  const float* srow = sx + (size_t)i*10;
  #pragma unroll
  for (int f=0;f<10;f++) sv[f] = srow[f];
  const float* __restrict__ G1  = W + O_G1;
  const float* __restrict__ G1b = W + O_G1b;
  const float* __restrict__ G2  = W + O_G2;
  float hw[64];
  #pragma unroll
  for (int f=0;f<64;f++) hw[f] = 0.f;
  #pragma unroll 1
  for (int k=0;k<64;k++){
    float o1 = G1b[k];
    #pragma unroll
    for (int j=0;j<10;j++) o1 = fmaf(sv[j], G1[j*64+k], o1);
    o1 = fmaxf(o1, 0.f);
    const float* __restrict__ wt = G2 + k*64;
    #pragma unroll
    for (int f=0;f<64;f++) hw[f] = fmaf(o1, wt[f], hw[f]);
  }
  const float* orow = oute + (size_t)i*64;
  #pragma unroll 1
  for (int k=0;k<64;k++){
    float ov = orow[k];                       // relu'd max (0 for isolated)
    const float* __restrict__ wb = G2 + (64+k)*64;
    #pragma unroll
    for (int f=0;f<64;f++) hw[f] = fmaf(ov, wb[f], hw[f]);
  }
  u16* out = hw2o + (size_t)i*64;
  #pragma unroll
  for (int f=0;f<64;f++) out[f] = f2bf(hw[f]);
}

// ---------- gcn2 aggregation: wave per node, lane = feature ----------
__global__ __launch_bounds__(256) void k_agg64(
    const u16* __restrict__ hw2, const int* __restrict__ rp,
    const int* __restrict__ csrc, const float* __restrict__ dis,
    const float* __restrict__ W, float* __restrict__ out2, int N_)
{
  int i = (blockIdx.x*256 + threadIdx.x) >> 6;
  int lane = threadIdx.x & 63;
  if (i >= N_) return;
  float di = dis[i];
  float acc = bfu(hw2[(size_t)i*64 + lane]) * di * di;
  int b = rp[i], en = rp[i+1];
  for (int p=b; p<en; p++){
    int s2 = csrc[p]; float nm = dis[s2]*di;
    acc = fmaf(bfu(hw2[(size_t)s2*64 + lane]), nm, acc);
  }
  float o2 = fmaxf(acc + (W+O_G2b)[lane], 0.f);
  out2[(size_t)i*64 + lane] = o2;
}

// ---------- hw3 = out2 @ gcn3_w (64->10), thread per node ----------
__global__ __launch_bounds__(256) void k_hw3(
    const float* __restrict__ out2, const float* __restrict__ W,
    float* __restrict__ hw3, int N_)
{
  int i = blockIdx.x*256 + threadIdx.x;
  if (i >= N_) return;
  const float* row = out2 + (size_t)i*64;
  const float* __restrict__ G3 = W + O_G3;
  float a[10];
  #pragma unroll
  for (int f=0;f<10;f++) a[f] = 0.f;
  #pragma unroll 1
  for (int k=0;k<64;k++){
    float v = row[k];
    const float* __restrict__ w = G3 + k*10;
    #pragma unroll
    for (int f=0;f<10;f++) a[f] = fmaf(v, w[f], a[f]);
  }
  float* o = hw3 + (size_t)i*10;
  #pragma unroll
  for (int f=0;f<10;f++) o[f] = a[f];
}

// ---------- gcn3 aggregation + MLP head -> FP32 output ----------
__global__ __launch_bounds__(256) void k_final(
    const void* __restrict__ xv, const float* __restrict__ hw3,
    const int* __restrict__ rp, const int* __restrict__ csrc,
    const float* __restrict__ dis, const int* __restrict__ flags,
    const float* __restrict__ W, float* __restrict__ out, int N_)
{
  int i = blockIdx.x*256 + threadIdx.x;
  if (i >= N_) return;
  int fx = flags[0];
  float di = dis[i];
  float a[10];
  const float* hrow = hw3 + (size_t)i*10;
  #pragma unroll
  for (int f=0;f<10;f++) a[f] = hrow[f]*di*di;
  int b = rp[i], en = rp[i+1];
  for (int p=b; p<en; p++){
    int s2 = csrc[p]; float nm = dis[s2]*di;
    const float* r2 = hw3 + (size_t)s2*10;
    #pragma unroll
    for (int f=0;f<10;f++) a[f] = fmaf(r2[f], nm, a[f]);
  }
  const float* G3b = W + O_G3b;
  float h20[20];
  load10_any(xv, (size_t)i, fx, h20);
  #pragma unroll
  for (int f=0;f<10;f++) h20[10+f] = fmaxf(a[f] + G3b[f], 0.f);
  const float* __restrict__ L1  = W + O_L1;
  const float* __restrict__ L1b = W + O_L1b;
  float h1[10];
  #pragma unroll
  for (int f=0;f<10;f++) h1[f] = L1b[f];
  #pragma unroll
  for (int k=0;k<20;k++){
    float v = h20[k];
    const float* __restrict__ w = L1 + k*10;
    #pragma unroll
    for (int f=0;f<10;f++) h1[f] = fmaf(v, w[f], h1[f]);
  }
  #pragma unroll
  for (int f=0;f<10;f++) h1[f] = softplusf(h1[f]);
  const float* __restrict__ L2t = W + O_L2t;
  const float* __restrict__ L2b = W + O_L2b;
  const float* __restrict__ L3  = W + O_L3;
  const float* __restrict__ L3b = W + O_L3b;
  float h3a[32];
  #pragma unroll
  for (int j=0;j<32;j++) h3a[j] = L3b[j];
  #pragma unroll 1
  for (int o=0;o<128;o++){
    float s2 = L2b[o];
    const float* __restrict__ wt = L2t + o*10;
    #pragma unroll
    for (int k=0;k<10;k++) s2 = fmaf(h1[k], wt[k], s2);
    s2 = softplusf(s2);
    const float* __restrict__ w3 = L3 + o*32;
    #pragma unroll
    for (int j=0;j<32;j++) h3a[j] = fmaf(s2, w3[j], h3a[j]);
  }
  const float* L4t = W + O_L4t;
  const float* L4b = W + O_L4b;
  float r0 = L4b[0], r1 = L4b[1];
  #pragma unroll
  for (int j=0;j<32;j++){
    float h3 = softplusf(h3a[j]);
    r0 = fmaf(h3, L4t[j],    r0);
    r1 = fmaf(h3, L4t[32+j], r1);
  }
  out[i]      = r0;
  out[N_ + i] = r1;
}

extern "C" void kernel_launch(void* const* d_in, const int* in_sizes, int n_in,
                              void* d_out, int out_size, void* d_ws, size_t ws_size,
                              hipStream_t stream)
{
  const void* xv  = d_in[0];
  const void* eav = d_in[1];
  const int*  ei  = (const int*)d_in[20];
  int N_ = in_sizes[0] / 10;
  int E_ = in_sizes[1] / 10;

  float* W = (float*)d_ws;
  size_t off = WTOT;
  int*   cnt   = (int*)(W + off);   off += (size_t)N_;
  int*   rp    = (int*)(W + off);   off += (size_t)N_ + 1;
  float* dis   = (float*)(W + off); off += (size_t)N_;
  int*   bsum  = (int*)(W + off);   off += 256;
  int*   boff  = (int*)(W + off);   off += 256;
  int*   flags = (int*)(W + off);   off += 32;
  int*   csrc  = (int*)(W + off);   off += (size_t)E_;
  int*   cedge = (int*)(W + off);   off += (size_t)E_;
  float* oute  = (float*)(W + off);          // [N,64] f32; reused as out2 after k_hw2
  float* out2  = oute;
  off += (size_t)N_ * 64;
  u16*   hw2   = (u16*)(W + off);   off += (size_t)N_ * 32;   // [N,64] bf16
  float* sx    = (float*)(W + off);          // [N,10]; reused as hw3
  float* hw3   = sx;
  off += (size_t)N_ * 10;

  if (ws_size < off * sizeof(float)) return;

  int gN = (N_ + 255)/256, gE = (E_ + 255)/256;
  int NB = (N_ + 1023)/1024;

  k_detect<<<20,256,0,stream>>>(
      (const u32*)d_in[0],(const u32*)d_in[1],
      (const u32*)d_in[2],(const u32*)d_in[3],(const u32*)d_in[4],(const u32*)d_in[5],
      (const u32*)d_in[6],(const u32*)d_in[7],(const u32*)d_in[8],(const u32*)d_in[9],
      (const u32*)d_in[10],(const u32*)d_in[11],(const u32*)d_in[12],(const u32*)d_in[13],
      (const u32*)d_in[14],(const u32*)d_in[15],(const u32*)d_in[16],(const u32*)d_in[17],
      (const u32*)d_in[18],(const u32*)d_in[19],
      flags, N_, E_);
  k_prep<<<1,256,0,stream>>>(
      d_in[2],d_in[3],d_in[4],d_in[5],d_in[6],d_in[7],d_in[8],d_in[9],
      d_in[10],d_in[11],d_in[12],d_in[13],d_in[14],d_in[15],d_in[16],d_in[17],
      d_in[18],d_in[19], flags, W);
  k_init<<<gN,256,0,stream>>>(cnt, N_);
  k_count<<<gE,256,0,stream>>>(ei, cnt, E_);
  k_bsum<<<NB,1024,0,stream>>>(cnt, bsum, N_);
  k_scan_small<<<1,128,0,stream>>>(bsum, boff, NB);
  k_scan_final<<<NB,1024,0,stream>>>(cnt, boff, rp, dis, N_, E_);
  k_fill<<<gE,256,0,stream>>>(ei, rp, cnt, csrc, cedge, E_);
  k_edgeconv<<<(N_+3)/4,256,0,stream>>>(xv, eav, rp, csrc, cedge, W, flags, oute, N_);
  k_aggx<<<gN,256,0,stream>>>(xv, rp, csrc, dis, flags, sx, N_);
  k_hw2<<<gN,256,0,stream>>>(sx, oute, W, hw2, N_);
  k_agg64<<<(N_+3)/4,256,0,stream>>>(hw2, rp, csrc, dis, W, out2, N_);
  k_hw3<<<gN,256,0,stream>>>(out2, W, hw3, N_);
  k_final<<<gN,256,0,stream>>>(xv, hw3, rp, csrc, dis, flags, W,
                               (float*)d_out, N_);
}